// Round 3
// baseline (553.093 us; speedup 1.0000x reference)
//
#include <hip/hip_runtime.h>
#include <cstdint>
#include <cstddef>

typedef unsigned short ushort_t;
typedef __attribute__((ext_vector_type(8))) __bf16 bf16x8;
typedef __attribute__((ext_vector_type(4))) float f32x4;

#define DEVINL __device__ __forceinline__

DEVINL ushort_t f2bf(float f) {
  union { float f; unsigned u; } v; v.f = f;
  unsigned r = (v.u + 0x7fffu + ((v.u >> 16) & 1u)) >> 16;
  return (ushort_t)r;
}

DEVINL float wred_sum(float x) {
#pragma unroll
  for (int o = 32; o > 0; o >>= 1) x += __shfl_xor(x, o, 64);
  return x;
}

// async global->LDS, 16B per lane (global_load_lds_dwordx4)
DEVINL void async16(ushort_t* lds, const ushort_t* g) {
  __builtin_amdgcn_global_load_lds(
      (__attribute__((address_space(1))) const unsigned int*)g,
      (__attribute__((address_space(3))) unsigned int*)lds, 16, 0, 0);
}

template <int CPR>
DEVINL int fswz(int r) {
  if constexpr (CPR == 4) return (r >> 2) & 3;
  else return r & 7;  // CPR==8
}

// ---------------- GroupNorm ----------------
__global__ __launch_bounds__(256) void gn_stats_k(const float* __restrict__ x,
                                                  float* __restrict__ stats) {
  const int bg = blockIdx.x;
  const float4* base = (const float4*)(x + ((size_t)bg << 16));
  float s = 0.f, q = 0.f;
  for (int i = threadIdx.x; i < 16384; i += 256) {
    float4 f = base[i];
    s += f.x + f.y + f.z + f.w;
    q += f.x * f.x + f.y * f.y + f.z * f.z + f.w * f.w;
  }
  s = wred_sum(s);
  q = wred_sum(q);
  __shared__ float rs[4], rq[4];
  const int lane = threadIdx.x & 63, wid = threadIdx.x >> 6;
  if (lane == 0) { rs[wid] = s; rq[wid] = q; }
  __syncthreads();
  if (threadIdx.x == 0) {
    float S = rs[0] + rs[1] + rs[2] + rs[3];
    float Q = rq[0] + rq[1] + rq[2] + rq[3];
    float mean = S * (1.f / 65536.f);
    float var = Q * (1.f / 65536.f) - mean * mean;
    stats[2 * bg] = mean;
    stats[2 * bg + 1] = rsqrtf(var + 1e-5f);
  }
}

__global__ __launch_bounds__(256) void gn_apply_k(const float* __restrict__ x,
                                                  const float* __restrict__ stats,
                                                  const float* __restrict__ gs,
                                                  const float* __restrict__ gb,
                                                  ushort_t* __restrict__ h) {
  __shared__ ushort_t tile[32][33];
  const int bid = blockIdx.x;
  const int b = bid >> 11;
  const int r = bid & 2047;
  const int ct = r >> 7, nt = r & 127;
  const int c0 = ct << 5, n0 = nt << 5;
  const int tx = threadIdx.x & 31, ty = threadIdx.x >> 5;
#pragma unroll
  for (int i = 0; i < 4; ++i) {
    const int c = c0 + ty + i * 8;
    const float mean = stats[2 * (b * 32 + (c >> 4))];
    const float rstd = stats[2 * (b * 32 + (c >> 4)) + 1];
    const float xv = x[(((size_t)b * 512 + c) << 12) + n0 + tx];
    tile[ty + i * 8][tx] = f2bf((xv - mean) * rstd * gs[c] + gb[c]);
  }
  __syncthreads();
#pragma unroll
  for (int i = 0; i < 4; ++i) {
    const int n = n0 + ty + i * 8;
    h[(((size_t)b << 12) + n) * 512 + c0 + tx] = tile[tx][ty + i * 8];
  }
}

// fp32 -> bf16 convert with per-matrix scale (sc folded into wq)
struct Ptr4 { const float* src[4]; float wsc[4]; };
__global__ __launch_bounds__(256) void cvt_all_k(Ptr4 s, ushort_t* __restrict__ dst) {
  const int i = blockIdx.x * 256 + threadIdx.x;
  const int m = i >> 18;
  dst[i] = f2bf(s.src[m][i & 262143] * s.wsc[m]);
}

// ---------------- NT GEMM (QKV + final) ----------------
struct Ptr3 { const float* bias[3]; ushort_t* out[3]; float bs[3]; };

template <int BM, int BN, int BK, int EPI>
__global__ __launch_bounds__(256) void gemm_nt_k(
    const ushort_t* __restrict__ A, int lda, const ushort_t* __restrict__ Bm, int ldb,
    void* __restrict__ Cout, int ldc, const float* __restrict__ bias,
    const float* __restrict__ resid, float scale, int K,
    size_t azs, size_t bzs, size_t czs, Ptr3 p3) {
  constexpr int CPR = BK / 8;
  constexpr int WTM = BM / 2, WTN = BN / 2;
  constexpr int MI = WTM / 16, NI = WTN / 16;
  constexpr int AR = (BM * CPR) / 256;
  constexpr int BR = (BN * CPR) / 256;
  __shared__ ushort_t Als[BM * BK];
  __shared__ ushort_t Bls[BN * BK];
  const int tid = threadIdx.x;
  const int lane = tid & 63;
  const int wid = tid >> 6;
  const int quad = lane >> 4;
  const int r16 = lane & 15;
  const int wm = wid >> 1, wn = wid & 1;
  const int m0 = blockIdx.y * BM;
  const int n0 = blockIdx.x * BN;
  const int zb = blockIdx.z;

  A += azs * zb;
  Bm += bzs * zb;

  f32x4 acc[MI][NI] = {};

  for (int kt = 0; kt < K; kt += BK) {
#pragma unroll
    for (int r = 0; r < AR; ++r) {
      const int s = r * 256 + tid;
      const int row = s / CPR;
      const int q = (s % CPR) ^ fswz<CPR>(row);
      async16(&Als[s << 3], A + (size_t)(m0 + row) * lda + kt + (q << 3));
    }
#pragma unroll
    for (int r = 0; r < BR; ++r) {
      const int s = r * 256 + tid;
      const int row = s / CPR;
      const int q = (s % CPR) ^ fswz<CPR>(row);
      async16(&Bls[s << 3], Bm + (size_t)(n0 + row) * ldb + kt + (q << 3));
    }
    __syncthreads();
#pragma unroll
    for (int kf = 0; kf < BK / 32; ++kf) {
      bf16x8 af[MI], bfr[NI];
#pragma unroll
      for (int mi = 0; mi < MI; ++mi) {
        const int lr = wm * WTM + mi * 16 + r16;
        const int ch = kf * 4 + quad;
        af[mi] = *reinterpret_cast<const bf16x8*>(
            &Als[(lr * CPR + (ch ^ fswz<CPR>(lr))) << 3]);
      }
#pragma unroll
      for (int ni = 0; ni < NI; ++ni) {
        const int lr = wn * WTN + ni * 16 + r16;
        const int ch = kf * 4 + quad;
        bfr[ni] = *reinterpret_cast<const bf16x8*>(
            &Bls[(lr * CPR + (ch ^ fswz<CPR>(lr))) << 3]);
      }
#pragma unroll
      for (int mi = 0; mi < MI; ++mi)
#pragma unroll
        for (int ni = 0; ni < NI; ++ni)
          acc[mi][ni] = __builtin_amdgcn_mfma_f32_16x16x32_bf16(
              af[mi], bfr[ni], acc[mi][ni], 0, 0, 0);
    }
    __syncthreads();
  }

  const int mrow = m0 + wm * WTM;
  const int ncol = n0 + wn * WTN;
  if constexpr (EPI == 2) {  // final: fp32 transposed out + resid + bias
    float* C = (float*)Cout;
#pragma unroll
    for (int ni = 0; ni < NI; ++ni) {
      const int col = ncol + ni * 16 + r16;
      const float bvv = bias[col];
#pragma unroll
      for (int mi = 0; mi < MI; ++mi) {
        const int rowb = mrow + mi * 16 + quad * 4;
        const int bb = rowb >> 12;
        const int nl = rowb & 4095;
        const size_t base = (((size_t)bb * 512 + col) << 12) + nl;
        const float4 rv = *(const float4*)&resid[base];
        float4 ov;
        ov.x = rv.x + acc[mi][ni][0] + bvv;
        ov.y = rv.y + acc[mi][ni][1] + bvv;
        ov.z = rv.z + acc[mi][ni][2] + bvv;
        ov.w = rv.w + acc[mi][ni][3] + bvv;
        *(float4*)&C[base] = ov;
      }
    }
  } else {  // EPI == 3: QKV, z picks weight/bias/out; z==2 (V) transposed
    const float* bz = p3.bias[zb];
    const float bsc = p3.bs[zb];
    ushort_t* O = p3.out[zb];
    if (zb < 2) {
#pragma unroll
      for (int ni = 0; ni < NI; ++ni) {
        const int col = ncol + ni * 16 + r16;
        const float bvv = bz[col] * bsc;
#pragma unroll
        for (int mi = 0; mi < MI; ++mi) {
          const int rowb = mrow + mi * 16 + quad * 4;
#pragma unroll
          for (int rr = 0; rr < 4; ++rr)
            O[(size_t)(rowb + rr) * 512 + col] = f2bf(acc[mi][ni][rr] + bvv);
        }
      }
    } else {
#pragma unroll
      for (int ni = 0; ni < NI; ++ni) {
        const int col = ncol + ni * 16 + r16;
        const float bvv = bz[col];
#pragma unroll
        for (int mi = 0; mi < MI; ++mi) {
          const int rowb = mrow + mi * 16 + quad * 4;
          const int bb = rowb >> 12;
          const int nn = rowb & 4095;
          ushort4 pk;
          pk.x = f2bf(acc[mi][ni][0] + bvv);
          pk.y = f2bf(acc[mi][ni][1] + bvv);
          pk.z = f2bf(acc[mi][ni][2] + bvv);
          pk.w = f2bf(acc[mi][ni][3] + bvv);
          *(ushort4*)&O[(((size_t)bb * 512 + col) << 12) + nn] = pk;
        }
      }
    }
  }
}

// ---------------- Flash attention: O = softmax(Q K^T) V ----------------
// One block: 64 Q-rows, 8 waves, full D=512 output. sc pre-folded into Q.
// LDS (ushort units): Q [0,32768) 64x512 CPR=64; K [32768,49152) 128x128 CPR=16;
// P [49152,57344) 64x128 CPR=16; V [57344,73728) 512x32 CPR=4; reductions after.
#define FLASH_LDS_BYTES 149504
__global__ __launch_bounds__(512, 2) void flash_k(
    const ushort_t* __restrict__ Qb, const ushort_t* __restrict__ Kb,
    const ushort_t* __restrict__ Vtb, ushort_t* __restrict__ Ob) {
  extern __shared__ ushort_t lds[];
  ushort_t* Qs = lds;
  ushort_t* Ks = lds + 32768;
  ushort_t* Ps = lds + 49152;
  ushort_t* Vs = lds + 57344;
  float* pmax = (float*)(lds + 73728);  // [4][64]
  float* psum = pmax + 256;             // [4][64]

  const int tid = threadIdx.x;
  const int lane = tid & 63;
  const int wid = tid >> 6;
  const int quad = lane >> 4;
  const int r16 = lane & 15;
  const int wm = wid >> 2;  // 0..1 (m split)
  const int wn = wid & 3;   // 0..3 (n split for S, c split for O)
  const int qb0 = blockIdx.x * 64;
  const int b = blockIdx.y;
  const size_t bofs = (size_t)b * 4096 * 512;

  // stage Q once: 64x512 bf16 = 4096 chunks, 8 rounds
  {
    const ushort_t* gq = Qb + bofs + (size_t)qb0 * 512;
#pragma unroll
    for (int r = 0; r < 8; ++r) {
      const int s = r * 512 + tid;
      const int row = s >> 6, ch = s & 63;
      async16(&Qs[s << 3], gq + row * 512 + ((ch ^ (row & 63)) << 3));
    }
  }

  f32x4 accO[2][8] = {};
  float m_i[2][4], l_i[2][4];
#pragma unroll
  for (int mi = 0; mi < 2; ++mi)
#pragma unroll
    for (int rr = 0; rr < 4; ++rr) { m_i[mi][rr] = -3.0e38f; l_i[mi][rr] = 0.f; }

  const int lrA = wm * 32 + r16;

  for (int tile = 0; tile < 32; ++tile) {
    const int kv0 = tile * 128;
    f32x4 accS[2][2] = {};
    // ---- S = Q K^T over D=512 in 4 chunks of 128
    for (int kt = 0; kt < 4; ++kt) {
      const ushort_t* gk = Kb + bofs + (size_t)kv0 * 512 + kt * 128;
#pragma unroll
      for (int r = 0; r < 4; ++r) {
        const int s = r * 512 + tid;
        const int row = s >> 4, ch = s & 15;
        async16(&Ks[s << 3], gk + row * 512 + ((ch ^ (row & 15)) << 3));
      }
      __syncthreads();
#pragma unroll
      for (int kf = 0; kf < 4; ++kf) {
        bf16x8 af[2], bf[2];
#pragma unroll
        for (int mi = 0; mi < 2; ++mi) {
          const int m = lrA + mi * 16;
          const int ch = kt * 16 + kf * 4 + quad;
          af[mi] = *(const bf16x8*)&Qs[(m * 64 + (ch ^ (m & 63))) << 3];
        }
#pragma unroll
        for (int ni = 0; ni < 2; ++ni) {
          const int n = wn * 32 + ni * 16 + r16;
          const int ch = kf * 4 + quad;
          bf[ni] = *(const bf16x8*)&Ks[(n * 16 + (ch ^ (n & 15))) << 3];
        }
#pragma unroll
        for (int mi = 0; mi < 2; ++mi)
#pragma unroll
          for (int ni = 0; ni < 2; ++ni)
            accS[mi][ni] = __builtin_amdgcn_mfma_f32_16x16x32_bf16(
                af[mi], bf[ni], accS[mi][ni], 0, 0, 0);
      }
      __syncthreads();
    }
    // ---- online softmax
    float alpha[2][4], mnew[2][4];
#pragma unroll
    for (int mi = 0; mi < 2; ++mi)
#pragma unroll
      for (int rr = 0; rr < 4; ++rr) {
        float t = fmaxf(accS[mi][0][rr], accS[mi][1][rr]);
#pragma unroll
        for (int o = 8; o >= 1; o >>= 1) t = fmaxf(t, __shfl_xor(t, o, 64));
        if (r16 == 0) pmax[wn * 64 + wm * 32 + mi * 16 + quad * 4 + rr] = t;
      }
    __syncthreads();
#pragma unroll
    for (int mi = 0; mi < 2; ++mi)
#pragma unroll
      for (int rr = 0; rr < 4; ++rr) {
        const int row = wm * 32 + mi * 16 + quad * 4 + rr;
        float mx = fmaxf(fmaxf(pmax[row], pmax[64 + row]),
                         fmaxf(pmax[128 + row], pmax[192 + row]));
        mx = fmaxf(mx, m_i[mi][rr]);
        mnew[mi][rr] = mx;
        alpha[mi][rr] = __expf(m_i[mi][rr] - mx);
        m_i[mi][rr] = mx;
      }
#pragma unroll
    for (int mi = 0; mi < 2; ++mi)
#pragma unroll
      for (int rr = 0; rr < 4; ++rr) {
        float p0 = __expf(accS[mi][0][rr] - mnew[mi][rr]);
        float p1 = __expf(accS[mi][1][rr] - mnew[mi][rr]);
        const int row = wm * 32 + mi * 16 + quad * 4 + rr;
        const int c0 = wn * 32 + r16;
        const int c1 = wn * 32 + 16 + r16;
        Ps[((row * 16 + ((c0 >> 3) ^ (row & 15))) << 3) + (c0 & 7)] = f2bf(p0);
        Ps[((row * 16 + ((c1 >> 3) ^ (row & 15))) << 3) + (c1 & 7)] = f2bf(p1);
        float t = p0 + p1;
#pragma unroll
        for (int o = 8; o >= 1; o >>= 1) t += __shfl_xor(t, o, 64);
        if (r16 == 0) psum[wn * 64 + row] = t;
      }
    __syncthreads();
#pragma unroll
    for (int mi = 0; mi < 2; ++mi)
#pragma unroll
      for (int rr = 0; rr < 4; ++rr) {
        const int row = wm * 32 + mi * 16 + quad * 4 + rr;
        float s = psum[row] + psum[64 + row] + psum[128 + row] + psum[192 + row];
        l_i[mi][rr] = l_i[mi][rr] * alpha[mi][rr] + s;
      }
#pragma unroll
    for (int mi = 0; mi < 2; ++mi)
#pragma unroll
      for (int ni = 0; ni < 8; ++ni)
#pragma unroll
        for (int rr = 0; rr < 4; ++rr)
          accO[mi][ni][rr] *= alpha[mi][rr];
    // ---- O += P V over kv=128 in 4 sub-chunks of 32
    for (int sub = 0; sub < 4; ++sub) {
      const ushort_t* gv = Vtb + bofs + kv0 + sub * 32;
#pragma unroll
      for (int r = 0; r < 4; ++r) {
        const int s = r * 512 + tid;
        const int row = s >> 2, ch = s & 3;
        async16(&Vs[s << 3], gv + (size_t)row * 4096 + ((ch ^ (row & 3)) << 3));
      }
      __syncthreads();
      bf16x8 pa[2];
#pragma unroll
      for (int mi = 0; mi < 2; ++mi) {
        const int m = lrA + mi * 16;
        const int ch = sub * 4 + quad;
        pa[mi] = *(const bf16x8*)&Ps[(m * 16 + (ch ^ (m & 15))) << 3];
      }
#pragma unroll
      for (int ni = 0; ni < 8; ++ni) {
        const int c = wn * 128 + ni * 16 + r16;
        bf16x8 vb = *(const bf16x8*)&Vs[(c * 4 + (quad ^ (c & 3))) << 3];
#pragma unroll
        for (int mi = 0; mi < 2; ++mi)
          accO[mi][ni] = __builtin_amdgcn_mfma_f32_16x16x32_bf16(
              pa[mi], vb, accO[mi][ni], 0, 0, 0);
      }
      __syncthreads();
    }
  }
  // epilogue: O /= l, write bf16 [b, n, c]
#pragma unroll
  for (int mi = 0; mi < 2; ++mi)
#pragma unroll
    for (int rr = 0; rr < 4; ++rr) {
      const float inv = 1.f / l_i[mi][rr];
      const int n = qb0 + wm * 32 + mi * 16 + quad * 4 + rr;
      ushort_t* op = Ob + bofs + (size_t)n * 512;
#pragma unroll
      for (int ni = 0; ni < 8; ++ni)
        op[wn * 128 + ni * 16 + r16] = f2bf(accO[mi][ni][rr] * inv);
    }
}

extern "C" void kernel_launch(void* const* d_in, const int* in_sizes, int n_in,
                              void* d_out, int out_size, void* d_ws, size_t ws_size,
                              hipStream_t stream) {
  const float* x  = (const float*)d_in[0];
  const float* gs = (const float*)d_in[1];
  const float* gb = (const float*)d_in[2];
  const float* wq = (const float*)d_in[3];
  const float* bq = (const float*)d_in[4];
  const float* wk = (const float*)d_in[5];
  const float* bk = (const float*)d_in[6];
  const float* wv = (const float*)d_in[7];
  const float* bv = (const float*)d_in[8];
  const float* wo = (const float*)d_in[9];
  const float* bo = (const float*)d_in[10];
  float* out = (float*)d_out;

  const size_t HNC = (size_t)4 * 4096 * 512;
  char* w = (char*)d_ws;
  float* stats  = (float*)w;    w += 4096;
  ushort_t* wb  = (ushort_t*)w; w += (size_t)4 * 262144 * 2;
  ushort_t* h   = (ushort_t*)w; w += HNC * 2;  // GN out; reused as O
  ushort_t* q   = (ushort_t*)w; w += HNC * 2;
  ushort_t* kk  = (ushort_t*)w; w += HNC * 2;
  ushort_t* vt  = (ushort_t*)w; w += HNC * 2;  // V transposed [B,C,N]

  const float sc = 0.044194173824159216f;  // 512^-0.5, folded into wq/bq

  hipFuncSetAttribute((const void*)flash_k,
                      hipFuncAttributeMaxDynamicSharedMemorySize, FLASH_LDS_BYTES);

  gn_stats_k<<<128, 256, 0, stream>>>(x, stats);
  gn_apply_k<<<8192, 256, 0, stream>>>(x, stats, gs, gb, h);
  Ptr4 wsrc;
  wsrc.src[0] = wq; wsrc.src[1] = wk; wsrc.src[2] = wv; wsrc.src[3] = wo;
  wsrc.wsc[0] = sc; wsrc.wsc[1] = 1.f; wsrc.wsc[2] = 1.f; wsrc.wsc[3] = 1.f;
  cvt_all_k<<<4096, 256, 0, stream>>>(wsrc, wb);

  Ptr3 qkv;
  qkv.bias[0] = bq; qkv.bias[1] = bk; qkv.bias[2] = bv;
  qkv.out[0] = q; qkv.out[1] = kk; qkv.out[2] = vt;
  qkv.bs[0] = sc; qkv.bs[1] = 1.f; qkv.bs[2] = 1.f;
  gemm_nt_k<128, 128, 32, 3><<<dim3(4, 128, 3), 256, 0, stream>>>(
      h, 512, wb, 512, nullptr, 0, nullptr, nullptr, 1.f, 512,
      0, 262144, 0, qkv);

  flash_k<<<dim3(64, 4), 512, FLASH_LDS_BYTES, stream>>>(q, kk, vt, h);

  Ptr3 e0{};
  gemm_nt_k<128, 128, 32, 2><<<dim3(4, 128, 1), 256, 0, stream>>>(
      h, 512, wb + (size_t)3 * 262144, 512, out, 512, bo, x, 1.f, 512,
      0, 0, 0, e0);
}

// Round 4
// 446.349 us; speedup vs baseline: 1.2392x; 1.2392x over previous
//
#include <hip/hip_runtime.h>
#include <cstdint>
#include <cstddef>

typedef unsigned short ushort_t;
typedef __attribute__((ext_vector_type(8))) __bf16 bf16x8;
typedef __attribute__((ext_vector_type(4))) float f32x4;

#define DEVINL __device__ __forceinline__

DEVINL ushort_t f2bf(float f) {
  union { float f; unsigned u; } v; v.f = f;
  unsigned r = (v.u + 0x7fffu + ((v.u >> 16) & 1u)) >> 16;
  return (ushort_t)r;
}

DEVINL float wred_sum(float x) {
#pragma unroll
  for (int o = 32; o > 0; o >>= 1) x += __shfl_xor(x, o, 64);
  return x;
}

// async global->LDS, 16B per lane (global_load_lds_dwordx4)
DEVINL void async16(ushort_t* lds, const ushort_t* g) {
  __builtin_amdgcn_global_load_lds(
      (__attribute__((address_space(1))) const unsigned int*)g,
      (__attribute__((address_space(3))) unsigned int*)lds, 16, 0, 0);
}

template <int CPR>
DEVINL int fswz(int r) {
  if constexpr (CPR == 4) return (r >> 2) & 3;
  else return r & 7;  // CPR==8
}

// ---------------- GroupNorm ----------------
__global__ __launch_bounds__(256) void gn_stats_k(const float* __restrict__ x,
                                                  float* __restrict__ stats) {
  const int bg = blockIdx.x;
  const float4* base = (const float4*)(x + ((size_t)bg << 16));
  float s = 0.f, q = 0.f;
  for (int i = threadIdx.x; i < 16384; i += 256) {
    float4 f = base[i];
    s += f.x + f.y + f.z + f.w;
    q += f.x * f.x + f.y * f.y + f.z * f.z + f.w * f.w;
  }
  s = wred_sum(s);
  q = wred_sum(q);
  __shared__ float rs[4], rq[4];
  const int lane = threadIdx.x & 63, wid = threadIdx.x >> 6;
  if (lane == 0) { rs[wid] = s; rq[wid] = q; }
  __syncthreads();
  if (threadIdx.x == 0) {
    float S = rs[0] + rs[1] + rs[2] + rs[3];
    float Q = rq[0] + rq[1] + rq[2] + rq[3];
    float mean = S * (1.f / 65536.f);
    float var = Q * (1.f / 65536.f) - mean * mean;
    stats[2 * bg] = mean;
    stats[2 * bg + 1] = rsqrtf(var + 1e-5f);
  }
}

__global__ __launch_bounds__(256) void gn_apply_k(const float* __restrict__ x,
                                                  const float* __restrict__ stats,
                                                  const float* __restrict__ gs,
                                                  const float* __restrict__ gb,
                                                  ushort_t* __restrict__ h) {
  __shared__ ushort_t tile[32][33];
  const int bid = blockIdx.x;
  const int b = bid >> 11;
  const int r = bid & 2047;
  const int ct = r >> 7, nt = r & 127;
  const int c0 = ct << 5, n0 = nt << 5;
  const int tx = threadIdx.x & 31, ty = threadIdx.x >> 5;
#pragma unroll
  for (int i = 0; i < 4; ++i) {
    const int c = c0 + ty + i * 8;
    const float mean = stats[2 * (b * 32 + (c >> 4))];
    const float rstd = stats[2 * (b * 32 + (c >> 4)) + 1];
    const float xv = x[(((size_t)b * 512 + c) << 12) + n0 + tx];
    tile[ty + i * 8][tx] = f2bf((xv - mean) * rstd * gs[c] + gb[c]);
  }
  __syncthreads();
#pragma unroll
  for (int i = 0; i < 4; ++i) {
    const int n = n0 + ty + i * 8;
    h[(((size_t)b << 12) + n) * 512 + c0 + tx] = tile[tx][ty + i * 8];
  }
}

// fp32 -> bf16 convert with per-matrix scale (sc folded into wq)
struct Ptr4 { const float* src[4]; float wsc[4]; };
__global__ __launch_bounds__(256) void cvt_all_k(Ptr4 s, ushort_t* __restrict__ dst) {
  const int i = blockIdx.x * 256 + threadIdx.x;
  const int m = i >> 18;
  dst[i] = f2bf(s.src[m][i & 262143] * s.wsc[m]);
}

// ---------------- NT GEMM (QKV + final) ----------------
struct Ptr3 { const float* bias[3]; ushort_t* out[3]; float bs[3]; };

template <int BM, int BN, int BK, int EPI>
__global__ __launch_bounds__(256) void gemm_nt_k(
    const ushort_t* __restrict__ A, int lda, const ushort_t* __restrict__ Bm, int ldb,
    void* __restrict__ Cout, int ldc, const float* __restrict__ bias,
    const float* __restrict__ resid, float scale, int K,
    size_t azs, size_t bzs, size_t czs, Ptr3 p3) {
  constexpr int CPR = BK / 8;
  constexpr int WTM = BM / 2, WTN = BN / 2;
  constexpr int MI = WTM / 16, NI = WTN / 16;
  constexpr int AR = (BM * CPR) / 256;
  constexpr int BR = (BN * CPR) / 256;
  __shared__ ushort_t Als[BM * BK];
  __shared__ ushort_t Bls[BN * BK];
  const int tid = threadIdx.x;
  const int lane = tid & 63;
  const int wid = tid >> 6;
  const int quad = lane >> 4;
  const int r16 = lane & 15;
  const int wm = wid >> 1, wn = wid & 1;
  const int m0 = blockIdx.y * BM;
  const int n0 = blockIdx.x * BN;
  const int zb = blockIdx.z;

  A += azs * zb;
  Bm += bzs * zb;

  f32x4 acc[MI][NI] = {};

  for (int kt = 0; kt < K; kt += BK) {
#pragma unroll
    for (int r = 0; r < AR; ++r) {
      const int s = r * 256 + tid;
      const int row = s / CPR;
      const int q = (s % CPR) ^ fswz<CPR>(row);
      async16(&Als[s << 3], A + (size_t)(m0 + row) * lda + kt + (q << 3));
    }
#pragma unroll
    for (int r = 0; r < BR; ++r) {
      const int s = r * 256 + tid;
      const int row = s / CPR;
      const int q = (s % CPR) ^ fswz<CPR>(row);
      async16(&Bls[s << 3], Bm + (size_t)(n0 + row) * ldb + kt + (q << 3));
    }
    __syncthreads();
#pragma unroll
    for (int kf = 0; kf < BK / 32; ++kf) {
      bf16x8 af[MI], bfr[NI];
#pragma unroll
      for (int mi = 0; mi < MI; ++mi) {
        const int lr = wm * WTM + mi * 16 + r16;
        const int ch = kf * 4 + quad;
        af[mi] = *reinterpret_cast<const bf16x8*>(
            &Als[(lr * CPR + (ch ^ fswz<CPR>(lr))) << 3]);
      }
#pragma unroll
      for (int ni = 0; ni < NI; ++ni) {
        const int lr = wn * WTN + ni * 16 + r16;
        const int ch = kf * 4 + quad;
        bfr[ni] = *reinterpret_cast<const bf16x8*>(
            &Bls[(lr * CPR + (ch ^ fswz<CPR>(lr))) << 3]);
      }
#pragma unroll
      for (int mi = 0; mi < MI; ++mi)
#pragma unroll
        for (int ni = 0; ni < NI; ++ni)
          acc[mi][ni] = __builtin_amdgcn_mfma_f32_16x16x32_bf16(
              af[mi], bfr[ni], acc[mi][ni], 0, 0, 0);
    }
    __syncthreads();
  }

  const int mrow = m0 + wm * WTM;
  const int ncol = n0 + wn * WTN;
  if constexpr (EPI == 2) {  // final: fp32 transposed out + resid + bias
    float* C = (float*)Cout;
#pragma unroll
    for (int ni = 0; ni < NI; ++ni) {
      const int col = ncol + ni * 16 + r16;
      const float bvv = bias[col];
#pragma unroll
      for (int mi = 0; mi < MI; ++mi) {
        const int rowb = mrow + mi * 16 + quad * 4;
        const int bb = rowb >> 12;
        const int nl = rowb & 4095;
        const size_t base = (((size_t)bb * 512 + col) << 12) + nl;
        const float4 rv = *(const float4*)&resid[base];
        float4 ov;
        ov.x = rv.x + acc[mi][ni][0] + bvv;
        ov.y = rv.y + acc[mi][ni][1] + bvv;
        ov.z = rv.z + acc[mi][ni][2] + bvv;
        ov.w = rv.w + acc[mi][ni][3] + bvv;
        *(float4*)&C[base] = ov;
      }
    }
  } else {  // EPI == 3: QKV, z picks weight/bias/out; z==2 (V) transposed
    const float* bz = p3.bias[zb];
    const float bsc = p3.bs[zb];
    ushort_t* O = p3.out[zb];
    if (zb < 2) {
#pragma unroll
      for (int ni = 0; ni < NI; ++ni) {
        const int col = ncol + ni * 16 + r16;
        const float bvv = bz[col] * bsc;
#pragma unroll
        for (int mi = 0; mi < MI; ++mi) {
          const int rowb = mrow + mi * 16 + quad * 4;
#pragma unroll
          for (int rr = 0; rr < 4; ++rr)
            O[(size_t)(rowb + rr) * 512 + col] = f2bf(acc[mi][ni][rr] + bvv);
        }
      }
    } else {
#pragma unroll
      for (int ni = 0; ni < NI; ++ni) {
        const int col = ncol + ni * 16 + r16;
        const float bvv = bz[col];
#pragma unroll
        for (int mi = 0; mi < MI; ++mi) {
          const int rowb = mrow + mi * 16 + quad * 4;
          const int bb = rowb >> 12;
          const int nn = rowb & 4095;
          ushort4 pk;
          pk.x = f2bf(acc[mi][ni][0] + bvv);
          pk.y = f2bf(acc[mi][ni][1] + bvv);
          pk.z = f2bf(acc[mi][ni][2] + bvv);
          pk.w = f2bf(acc[mi][ni][3] + bvv);
          *(ushort4*)&O[(((size_t)bb * 512 + col) << 12) + nn] = pk;
        }
      }
    }
  }
}

// ---------------- Flash attention v2 ----------------
// 512 thr (8 waves), BM=64 Q-rows/block, KV-tile=256, 16 tiles.
// Per tile: 8 S-phases (stage Qc[64][64]+Kc[256][64] = 40KB) then 8 PV-phases
// (stage Vc[512][32kv] = 32KB), ping-pong across two 40KB buffers with ONE
// barrier per phase (stage next AFTER barrier -> loads fly during compute).
// Waves: (wm 0..1) x (wk 0..3). S: wave-tile 32 rows x 64 kv (af2+bf4 -> 8 MFMA
// per kchunk). PV: wave-tile 32 rows x 128 D (pa2+vb8 -> 16 MFMA per phase).
// Softmax: band stats shared across the 4 kv-waves via 2KB red region,
// 2 barriers per 256-kv tile. P (exp, bf16) in LDS [64][256] rows padded to 264.
#define FLASH_LDS_BYTES 117760
__global__ __launch_bounds__(512, 2) void flash_k(
    const ushort_t* __restrict__ Qb, const ushort_t* __restrict__ Kb,
    const ushort_t* __restrict__ Vtb, ushort_t* __restrict__ Ob) {
  extern __shared__ ushort_t lds[];
  ushort_t* Pl = lds + 40960;               // [64][264] ush = 33792 B
  float* redmax = (float*)(lds + 57856);    // [64][4]
  float* redsum = redmax + 256;             // [64][4]

  const int tid = threadIdx.x;
  const int lane = tid & 63;
  const int wid = tid >> 6;
  const int quad = lane >> 4;
  const int r16 = lane & 15;
  const int wm = wid >> 2;   // 0..1 row band
  const int wk = wid & 3;    // 0..3 kv-split (S) / D-split (PV)
  const int qb0 = blockIdx.x * 64;
  const int b = blockIdx.y;
  const size_t bofs = (size_t)b * 4096 * 512;
  const ushort_t* qg = Qb + bofs + (size_t)qb0 * 512;
  const ushort_t* kg = Kb + bofs;
  const ushort_t* vg = Vtb + bofs;

  auto stage_S = [&](int buf, int t, int p) {
    ushort_t* dst = lds + buf * 20480;
    const int dofs = p * 64;
    {  // Qc: 512 slots (1/thread), swizzled chunks within 128B row segments
      const int row = tid >> 3, c = tid & 7;
      async16(dst + ((size_t)tid << 3),
              qg + row * 512 + dofs + ((c ^ (row & 7)) << 3));
    }
    const ushort_t* kt = kg + ((size_t)t * 256) * 512 + dofs;
#pragma unroll
    for (int r = 0; r < 4; ++r) {  // Kc: 2048 slots
      const int s = r * 512 + tid;
      const int row = s >> 3, c = s & 7;
      async16(dst + ((size_t)(512 + s) << 3),
              kt + row * 512 + ((c ^ (row & 7)) << 3));
    }
  };
  auto stage_PV = [&](int buf, int t, int p) {
    ushort_t* dst = lds + buf * 20480;
    const ushort_t* vt0 = vg + t * 256 + p * 32;
#pragma unroll
    for (int r = 0; r < 4; ++r) {  // Vc: 2048 slots [512ch][4 chunks]
      const int s = r * 512 + tid;
      const int ch = s >> 2, c = s & 3;
      async16(dst + ((size_t)s << 3),
              vt0 + (size_t)ch * 4096 + ((c ^ (ch & 3)) << 3));
    }
  };

  f32x4 accO[2][8] = {};
  float m_i[2][4], l_i[2][4];
#pragma unroll
  for (int mi = 0; mi < 2; ++mi)
#pragma unroll
    for (int rr = 0; rr < 4; ++rr) { m_i[mi][rr] = -3.0e38f; l_i[mi][rr] = 0.f; }

  stage_S(0, 0, 0);
  int buf = 0;

  for (int t = 0; t < 16; ++t) {
    f32x4 accS[2][4] = {};
    // ---- S phases: accumulate S(64x256) over D=512 in 8 chunks of 64
    for (int p = 0; p < 8; ++p) {
      __syncthreads();  // drains stage(p); stage(p+1) issued below, in flight
      if (p < 7) stage_S(buf ^ 1, t, p + 1);
      else stage_PV(buf ^ 1, t, 0);
      const ushort_t* sb = lds + buf * 20480;
#pragma unroll
      for (int kc = 0; kc < 2; ++kc) {
        bf16x8 af[2], bf[4];
#pragma unroll
        for (int mi = 0; mi < 2; ++mi) {
          const int row = wm * 32 + mi * 16 + r16;
          af[mi] = *(const bf16x8*)
              &sb[(row * 8 + ((kc * 4 + quad) ^ (row & 7))) << 3];
        }
#pragma unroll
        for (int ni = 0; ni < 4; ++ni) {
          const int kr = wk * 64 + ni * 16 + r16;
          bf[ni] = *(const bf16x8*)
              &sb[(512 + kr * 8 + ((kc * 4 + quad) ^ (kr & 7))) << 3];
        }
#pragma unroll
        for (int mi = 0; mi < 2; ++mi)
#pragma unroll
          for (int ni = 0; ni < 4; ++ni)
            accS[mi][ni] = __builtin_amdgcn_mfma_f32_16x16x32_bf16(
                af[mi], bf[ni], accS[mi][ni], 0, 0, 0);
      }
      buf ^= 1;
    }
    // ---- online softmax over the 256-kv tile
    float mnew[2][4], alpha[2][4];
#pragma unroll
    for (int mi = 0; mi < 2; ++mi)
#pragma unroll
      for (int rr = 0; rr < 4; ++rr) {
        float mx = fmaxf(fmaxf(accS[mi][0][rr], accS[mi][1][rr]),
                         fmaxf(accS[mi][2][rr], accS[mi][3][rr]));
#pragma unroll
        for (int o = 8; o >= 1; o >>= 1) mx = fmaxf(mx, __shfl_xor(mx, o, 64));
        if (r16 == 0)
          redmax[(wm * 32 + mi * 16 + quad * 4 + rr) * 4 + wk] = mx;
      }
    __syncthreads();
#pragma unroll
    for (int mi = 0; mi < 2; ++mi)
#pragma unroll
      for (int rr = 0; rr < 4; ++rr) {
        const int row = wm * 32 + mi * 16 + quad * 4 + rr;
        float mx = fmaxf(fmaxf(redmax[row * 4], redmax[row * 4 + 1]),
                         fmaxf(redmax[row * 4 + 2], redmax[row * 4 + 3]));
        mx = fmaxf(mx, m_i[mi][rr]);
        mnew[mi][rr] = mx;
        alpha[mi][rr] = __expf(m_i[mi][rr] - mx);
        m_i[mi][rr] = mx;
      }
#pragma unroll
    for (int mi = 0; mi < 2; ++mi)
#pragma unroll
      for (int rr = 0; rr < 4; ++rr) {
        const int row = wm * 32 + mi * 16 + quad * 4 + rr;
        float ps = 0.f;
#pragma unroll
        for (int ni = 0; ni < 4; ++ni) {
          float e = __expf(accS[mi][ni][rr] - mnew[mi][rr]);
          ps += e;
          Pl[row * 264 + wk * 64 + ni * 16 + r16] = f2bf(e);
        }
#pragma unroll
        for (int o = 8; o >= 1; o >>= 1) ps += __shfl_xor(ps, o, 64);
        if (r16 == 0) redsum[row * 4 + wk] = ps;
      }
    __syncthreads();  // publishes P and redsum
#pragma unroll
    for (int mi = 0; mi < 2; ++mi)
#pragma unroll
      for (int rr = 0; rr < 4; ++rr) {
        const int row = wm * 32 + mi * 16 + quad * 4 + rr;
        const float s = redsum[row * 4] + redsum[row * 4 + 1] +
                        redsum[row * 4 + 2] + redsum[row * 4 + 3];
        l_i[mi][rr] = l_i[mi][rr] * alpha[mi][rr] + s;
      }
#pragma unroll
    for (int mi = 0; mi < 2; ++mi)
#pragma unroll
      for (int ni = 0; ni < 8; ++ni)
#pragma unroll
        for (int rr = 0; rr < 4; ++rr)
          accO[mi][ni][rr] *= alpha[mi][rr];
    // ---- PV phases: O(64x512) += P(64x256) V(256x512), kv-chunks of 32
    for (int p = 0; p < 8; ++p) {
      __syncthreads();
      if (p < 7) stage_PV(buf ^ 1, t, p + 1);
      else if (t < 15) stage_S(buf ^ 1, t + 1, 0);
      const ushort_t* sb = lds + buf * 20480;
      bf16x8 pa[2];
#pragma unroll
      for (int mi = 0; mi < 2; ++mi) {
        const int pr = wm * 32 + mi * 16 + r16;
        pa[mi] = *(const bf16x8*)&Pl[pr * 264 + (p * 4 + quad) * 8];
      }
#pragma unroll
      for (int ni = 0; ni < 8; ++ni) {
        const int ch = wk * 128 + ni * 16 + r16;
        bf16x8 vb = *(const bf16x8*)&sb[(ch * 4 + (quad ^ (ch & 3))) << 3];
#pragma unroll
        for (int mi = 0; mi < 2; ++mi)
          accO[mi][ni] = __builtin_amdgcn_mfma_f32_16x16x32_bf16(
              pa[mi], vb, accO[mi][ni], 0, 0, 0);
      }
      buf ^= 1;
    }
  }
  // epilogue: O /= l, write bf16 [b, n, c]
#pragma unroll
  for (int mi = 0; mi < 2; ++mi)
#pragma unroll
    for (int rr = 0; rr < 4; ++rr) {
      const float inv = 1.f / l_i[mi][rr];
      const int n = qb0 + wm * 32 + mi * 16 + quad * 4 + rr;
      ushort_t* op = Ob + bofs + (size_t)n * 512 + wk * 128;
#pragma unroll
      for (int ni = 0; ni < 8; ++ni)
        op[ni * 16 + r16] = f2bf(accO[mi][ni][rr] * inv);
    }
}

extern "C" void kernel_launch(void* const* d_in, const int* in_sizes, int n_in,
                              void* d_out, int out_size, void* d_ws, size_t ws_size,
                              hipStream_t stream) {
  const float* x  = (const float*)d_in[0];
  const float* gs = (const float*)d_in[1];
  const float* gb = (const float*)d_in[2];
  const float* wq = (const float*)d_in[3];
  const float* bq = (const float*)d_in[4];
  const float* wk = (const float*)d_in[5];
  const float* bk = (const float*)d_in[6];
  const float* wv = (const float*)d_in[7];
  const float* bv = (const float*)d_in[8];
  const float* wo = (const float*)d_in[9];
  const float* bo = (const float*)d_in[10];
  float* out = (float*)d_out;

  const size_t HNC = (size_t)4 * 4096 * 512;
  char* w = (char*)d_ws;
  float* stats  = (float*)w;    w += 4096;
  ushort_t* wb  = (ushort_t*)w; w += (size_t)4 * 262144 * 2;
  ushort_t* h   = (ushort_t*)w; w += HNC * 2;  // GN out; reused as O
  ushort_t* q   = (ushort_t*)w; w += HNC * 2;
  ushort_t* kk  = (ushort_t*)w; w += HNC * 2;
  ushort_t* vt  = (ushort_t*)w; w += HNC * 2;  // V transposed [B,C,N]

  const float sc = 0.044194173824159216f;  // 512^-0.5, folded into wq/bq

  hipFuncSetAttribute((const void*)flash_k,
                      hipFuncAttributeMaxDynamicSharedMemorySize, FLASH_LDS_BYTES);

  gn_stats_k<<<128, 256, 0, stream>>>(x, stats);
  gn_apply_k<<<8192, 256, 0, stream>>>(x, stats, gs, gb, h);
  Ptr4 wsrc;
  wsrc.src[0] = wq; wsrc.src[1] = wk; wsrc.src[2] = wv; wsrc.src[3] = wo;
  wsrc.wsc[0] = sc; wsrc.wsc[1] = 1.f; wsrc.wsc[2] = 1.f; wsrc.wsc[3] = 1.f;
  cvt_all_k<<<4096, 256, 0, stream>>>(wsrc, wb);

  Ptr3 qkv;
  qkv.bias[0] = bq; qkv.bias[1] = bk; qkv.bias[2] = bv;
  qkv.out[0] = q; qkv.out[1] = kk; qkv.out[2] = vt;
  qkv.bs[0] = sc; qkv.bs[1] = 1.f; qkv.bs[2] = 1.f;
  gemm_nt_k<128, 128, 32, 3><<<dim3(4, 128, 3), 256, 0, stream>>>(
      h, 512, wb, 512, nullptr, 0, nullptr, nullptr, 1.f, 512,
      0, 262144, 0, qkv);

  flash_k<<<dim3(64, 4), 512, FLASH_LDS_BYTES, stream>>>(q, kk, vt, h);

  Ptr3 e0{};
  gemm_nt_k<128, 128, 32, 2><<<dim3(4, 128, 1), 256, 0, stream>>>(
      h, 512, wb + (size_t)3 * 262144, 512, out, 512, bo, x, 1.f, 512,
      0, 0, 0, e0);
}